// Round 3
// baseline (216.649 us; speedup 1.0000x reference)
//
#include <hip/hip_runtime.h>
#include <math.h>

constexpr int BB = 2, NN = 4096, MM = 16384;
constexpr int RT = 256, CT = 256;        // block tile (rows=sampled, cols=raw)
constexpr unsigned INFBITS = 0x7F800000u;

__global__ __launch_bounds__(256) void init_ws_kernel(unsigned* ws, int n) {
    int i = blockIdx.x * 256 + threadIdx.x;
    if (i < n) ws[i] = INFBITS;
}

// grid (MM/CT, NN/RT, BB) = (64,16,2); block 256 = 16 tx (cols) x 16 ty (rows)
// Thread tile: 16 rows x 16 cols, all points in registers, no LDS/shfl in loop.
__global__ __launch_bounds__(256, 2) void pair_kernel(
    const float* __restrict__ sampled,   // [BB][NN][4]
    const float* __restrict__ raw,       // [BB][MM][4]
    unsigned* __restrict__ rowmin,       // [BB][NN]  float bits, atomicMin
    unsigned* __restrict__ colmin)       // [BB][MM]  float bits, atomicMin
{
    const int b  = blockIdx.z;
    const int i0 = blockIdx.y * RT;
    const int j0 = blockIdx.x * CT;
    const int tid = threadIdx.x;
    const int tx = tid & 15, ty = tid >> 4;

    const float4* sb = (const float4*)sampled + (size_t)b * NN + i0;
    const float4* rb = (const float4*)raw     + (size_t)b * MM + j0;

    float sx[16], sy[16], sz[16], sw[16];
#pragma unroll
    for (int q = 0; q < 16; ++q) {
        float4 v = sb[ty * 16 + q];
        sx[q] = v.x; sy[q] = v.y; sz[q] = v.z;
        sw[q] = fmaf(v.z, v.z, fmaf(v.y, v.y, v.x * v.x));
    }
    float rx[16], ry[16], rz[16], rw[16];
#pragma unroll
    for (int r = 0; r < 16; ++r) {
        float4 v = rb[tx * 16 + r];
        rw[r] = fmaf(v.z, v.z, fmaf(v.y, v.y, v.x * v.x));
        rx[r] = -2.f * v.x; ry[r] = -2.f * v.y; rz[r] = -2.f * v.z;
    }

    const float INF = __uint_as_float(INFBITS);
    float rmin[16], cmin[16];
#pragma unroll
    for (int k = 0; k < 16; ++k) { rmin[k] = INF; cmin[k] = INF; }

#pragma unroll
    for (int q = 0; q < 16; ++q) {
#pragma unroll
        for (int r = 0; r < 16; ++r) {
            float a = sw[q] + rw[r];
            a = fmaf(sx[q], rx[r], a);
            a = fmaf(sy[q], ry[r], a);
            a = fmaf(sz[q], rz[r], a);
            rmin[q] = fminf(rmin[q], a);
            cmin[r] = fminf(cmin[r], a);
        }
    }

    // ---- row mins: reduce across the 16 tx lanes (in-wave, same ty group) ----
#pragma unroll
    for (int m = 1; m < 16; m <<= 1) {
#pragma unroll
        for (int q = 0; q < 16; ++q)
            rmin[q] = fminf(rmin[q], __shfl_xor(rmin[q], m, 64));
    }
    if (tx == 0) {
#pragma unroll
        for (int q = 0; q < 16; ++q)
            atomicMin(&rowmin[(size_t)b * NN + i0 + ty * 16 + q],
                      __float_as_uint(fmaxf(rmin[q], 0.f)));
    }

    // ---- col mins: reduce across ty. In-wave: masks 16,32; cross-wave: LDS ----
#pragma unroll
    for (int m = 16; m < 64; m <<= 1) {
#pragma unroll
        for (int r = 0; r < 16; ++r)
            cmin[r] = fminf(cmin[r], __shfl_xor(cmin[r], m, 64));
    }
    __shared__ float cred[4][CT];        // 4 KB
    const int w = tid >> 6, lane = tid & 63;
    if (lane < 16) {
#pragma unroll
        for (int r = 0; r < 16; ++r) cred[w][lane * 16 + r] = cmin[r];
    }
    __syncthreads();
    {
        float v = fminf(fminf(cred[0][tid], cred[1][tid]),
                        fminf(cred[2][tid], cred[3][tid]));
        atomicMin(&colmin[(size_t)b * MM + j0 + tid],
                  __float_as_uint(fmaxf(v, 0.f)));
    }
}

// Single block, 1024 threads = 16 waves. Waves 0-7 -> b0, 8-15 -> b1.
__global__ __launch_bounds__(1024) void final_kernel(
    const unsigned* __restrict__ rowmin,
    const unsigned* __restrict__ colmin,
    float* __restrict__ out)
{
    const int tid = threadIdx.x;
    const int b = tid >> 9, t = tid & 511;
    const int lane = tid & 63, wv = tid >> 6;

    float sB = 0.f;
    const unsigned* cm = colmin + (size_t)b * MM;
    for (int j = t; j < MM; j += 512) sB += sqrtf(__uint_as_float(cm[j]));

    float sF = 0.f, mF = 0.f;
    const unsigned* rm = rowmin + (size_t)b * NN;
    for (int i = t; i < NN; i += 512) {
        float d = sqrtf(__uint_as_float(rm[i]));
        sF += d; mF = fmaxf(mF, d);
    }
    for (int m = 1; m < 64; m <<= 1) {
        sB += __shfl_xor(sB, m, 64);
        sF += __shfl_xor(sF, m, 64);
        mF = fmaxf(mF, __shfl_xor(mF, m, 64));
    }
    __shared__ float red[16][3];
    if (lane == 0) { red[wv][0] = sB; red[wv][1] = sF; red[wv][2] = mF; }
    __syncthreads();
    if (tid == 0) {
        float total = 0.f;
        for (int bb = 0; bb < BB; ++bb) {
            float aB = 0.f, aF = 0.f, aM = 0.f;
            for (int k = 0; k < 8; ++k) {
                aB += red[bb * 8 + k][0];
                aF += red[bb * 8 + k][1];
                aM = fmaxf(aM, red[bb * 8 + k][2]);
            }
            total += 5.f * aB / (float)MM + aF / (float)NN + aM;
        }
        *out = total / (float)BB;
    }
}

extern "C" void kernel_launch(void* const* d_in, const int* in_sizes, int n_in,
                              void* d_out, int out_size, void* d_ws, size_t ws_size,
                              hipStream_t stream) {
    const float* sampled = (const float*)d_in[0];
    const float* raw     = (const float*)d_in[1];
    unsigned* rowmin = (unsigned*)d_ws;
    unsigned* colmin = rowmin + (size_t)BB * NN;
    float*    out    = (float*)d_out;

    const int ninit = BB * NN + BB * MM;
    init_ws_kernel<<<(ninit + 255) / 256, 256, 0, stream>>>((unsigned*)d_ws, ninit);
    pair_kernel<<<dim3(MM / CT, NN / RT, BB), 256, 0, stream>>>(sampled, raw, rowmin, colmin);
    final_kernel<<<1, 1024, 0, stream>>>(rowmin, colmin, out);
}

// Round 4
// 97.139 us; speedup vs baseline: 2.2303x; 2.2303x over previous
//
#include <hip/hip_runtime.h>
#include <math.h>

constexpr int BB = 2, NN = 4096, MM = 16384;
constexpr int RT = 128, CT = 128;        // block tile (rows=sampled, cols=raw)
constexpr unsigned INFBITS = 0x7F800000u;

__global__ __launch_bounds__(256) void init_ws_kernel(unsigned* ws, int n) {
    int i = blockIdx.x * 256 + threadIdx.x;
    if (i < n) ws[i] = INFBITS;
}

// grid (MM/CT, NN/RT, BB) = (128,32,2); block 256 = 16 tx (cols) x 16 ty (rows)
// Thread tile: 8 rows x 8 cols in registers (~110 VGPR, fits 128-reg budget).
// Points staged once in LDS per block; inner loop pure VALU.
__global__ __launch_bounds__(256, 4) void pair_kernel(
    const float* __restrict__ sampled,   // [BB][NN][4]
    const float* __restrict__ raw,       // [BB][MM][4]
    unsigned* __restrict__ rowmin,       // [BB][NN]  float bits, atomicMin
    unsigned* __restrict__ colmin)       // [BB][MM]  float bits, atomicMin
{
    __shared__ float4 sT[RT];            // (x, y, z, |s|^2)        2 KB
    __shared__ float4 rT[CT];            // (-2x, -2y, -2z, |r|^2)  2 KB
    __shared__ float cred[4][CT];        //                         2 KB

    const int b  = blockIdx.z;
    const int i0 = blockIdx.y * RT;
    const int j0 = blockIdx.x * CT;
    const int tid = threadIdx.x;
    const int tx = tid & 15, ty = tid >> 4;

    const float4* sb = (const float4*)sampled + (size_t)b * NN + i0;
    const float4* rb = (const float4*)raw     + (size_t)b * MM + j0;

    // cooperative stage: one point per thread, norms folded in
    if (tid < RT) {
        float4 v = sb[tid];
        v.w = fmaf(v.z, v.z, fmaf(v.y, v.y, v.x * v.x));
        sT[tid] = v;
    } else {
        float4 v = rb[tid - RT];
        float w = fmaf(v.z, v.z, fmaf(v.y, v.y, v.x * v.x));
        rT[tid - RT] = make_float4(-2.f * v.x, -2.f * v.y, -2.f * v.z, w);
    }
    __syncthreads();

    float sx[8], sy[8], sz[8], sw[8];
#pragma unroll
    for (int q = 0; q < 8; ++q) {
        float4 v = sT[ty * 8 + q];
        sx[q] = v.x; sy[q] = v.y; sz[q] = v.z; sw[q] = v.w;
    }
    float rx[8], ry[8], rz[8], rw[8];
#pragma unroll
    for (int r = 0; r < 8; ++r) {
        float4 v = rT[tx * 8 + r];
        rx[r] = v.x; ry[r] = v.y; rz[r] = v.z; rw[r] = v.w;
    }

    const float INF = __uint_as_float(INFBITS);
    float cmin[8] = {INF, INF, INF, INF, INF, INF, INF, INF};
    float rmin[8];

#pragma unroll
    for (int q = 0; q < 8; ++q) {
        float a[8];
#pragma unroll
        for (int r = 0; r < 8; ++r) {
            float t = sw[q] + rw[r];
            t = fmaf(sx[q], rx[r], t);
            t = fmaf(sy[q], ry[r], t);
            t = fmaf(sz[q], rz[r], t);
            a[r] = t;
            cmin[r] = fminf(cmin[r], t);
        }
        float m0 = fminf(fminf(a[0], a[1]), fminf(a[2], a[3]));
        float m1 = fminf(fminf(a[4], a[5]), fminf(a[6], a[7]));
        rmin[q] = fminf(m0, m1);
    }

    // ---- row mins: butterfly across the 16 tx lanes (in-wave) ----
#pragma unroll
    for (int m = 1; m < 16; m <<= 1) {
#pragma unroll
        for (int q = 0; q < 8; ++q)
            rmin[q] = fminf(rmin[q], __shfl_xor(rmin[q], m, 64));
    }
    if (tx == 0) {
#pragma unroll
        for (int q = 0; q < 8; ++q)
            atomicMin(&rowmin[(size_t)b * NN + i0 + ty * 8 + q],
                      __float_as_uint(fmaxf(rmin[q], 0.f)));
    }

    // ---- col mins: in-wave across ty (masks 16,32), then LDS across waves ----
#pragma unroll
    for (int m = 16; m < 64; m <<= 1) {
#pragma unroll
        for (int r = 0; r < 8; ++r)
            cmin[r] = fminf(cmin[r], __shfl_xor(cmin[r], m, 64));
    }
    const int w = tid >> 6, lane = tid & 63;
    if (lane < 16) {
#pragma unroll
        for (int r = 0; r < 8; ++r) cred[w][lane * 8 + r] = cmin[r];
    }
    __syncthreads();
    if (tid < CT) {
        float v = fminf(fminf(cred[0][tid], cred[1][tid]),
                        fminf(cred[2][tid], cred[3][tid]));
        atomicMin(&colmin[(size_t)b * MM + j0 + tid],
                  __float_as_uint(fmaxf(v, 0.f)));
    }
}

// Single block, 1024 threads = 16 waves. Waves 0-7 -> b0, 8-15 -> b1.
__global__ __launch_bounds__(1024) void final_kernel(
    const unsigned* __restrict__ rowmin,
    const unsigned* __restrict__ colmin,
    float* __restrict__ out)
{
    const int tid = threadIdx.x;
    const int b = tid >> 9, t = tid & 511;
    const int lane = tid & 63, wv = tid >> 6;

    float sB = 0.f;
    const unsigned* cm = colmin + (size_t)b * MM;
    for (int j = t; j < MM; j += 512) sB += sqrtf(__uint_as_float(cm[j]));

    float sF = 0.f, mF = 0.f;
    const unsigned* rm = rowmin + (size_t)b * NN;
    for (int i = t; i < NN; i += 512) {
        float d = sqrtf(__uint_as_float(rm[i]));
        sF += d; mF = fmaxf(mF, d);
    }
    for (int m = 1; m < 64; m <<= 1) {
        sB += __shfl_xor(sB, m, 64);
        sF += __shfl_xor(sF, m, 64);
        mF = fmaxf(mF, __shfl_xor(mF, m, 64));
    }
    __shared__ float red[16][3];
    if (lane == 0) { red[wv][0] = sB; red[wv][1] = sF; red[wv][2] = mF; }
    __syncthreads();
    if (tid == 0) {
        float total = 0.f;
        for (int bb = 0; bb < BB; ++bb) {
            float aB = 0.f, aF = 0.f, aM = 0.f;
            for (int k = 0; k < 8; ++k) {
                aB += red[bb * 8 + k][0];
                aF += red[bb * 8 + k][1];
                aM = fmaxf(aM, red[bb * 8 + k][2]);
            }
            total += 5.f * aB / (float)MM + aF / (float)NN + aM;
        }
        *out = total / (float)BB;
    }
}

extern "C" void kernel_launch(void* const* d_in, const int* in_sizes, int n_in,
                              void* d_out, int out_size, void* d_ws, size_t ws_size,
                              hipStream_t stream) {
    const float* sampled = (const float*)d_in[0];
    const float* raw     = (const float*)d_in[1];
    unsigned* rowmin = (unsigned*)d_ws;
    unsigned* colmin = rowmin + (size_t)BB * NN;
    float*    out    = (float*)d_out;

    const int ninit = BB * NN + BB * MM;
    init_ws_kernel<<<(ninit + 255) / 256, 256, 0, stream>>>((unsigned*)d_ws, ninit);
    pair_kernel<<<dim3(MM / CT, NN / RT, BB), 256, 0, stream>>>(sampled, raw, rowmin, colmin);
    final_kernel<<<1, 1024, 0, stream>>>(rowmin, colmin, out);
}

// Round 5
// 95.514 us; speedup vs baseline: 2.2683x; 1.0170x over previous
//
#include <hip/hip_runtime.h>
#include <math.h>

constexpr int BB = 2, NN = 4096, MM = 16384;
constexpr int RT = 128, CT = 128;        // block tile (rows=sampled, cols=raw)
constexpr unsigned INFBITS = 0x7F800000u;

__global__ __launch_bounds__(256) void init_ws_kernel(unsigned* ws, int n) {
    int i = blockIdx.x * 256 + threadIdx.x;
    if (i < n) ws[i] = INFBITS;
}

// grid (MM/CT, NN/RT, BB) = (128,32,2); block 256 = 16 tx (cols) x 16 ty (rows)
// 8x8 thread tile. Points staged in SoA LDS (swizzled, <=2-way banks), pulled
// to registers ONCE and pinned there with inline asm so the allocator cannot
// sink the LDS reads into the loop (R4 failure: VGPR=48, 8.3M bank conflicts).
__global__ __launch_bounds__(256, 4) void pair_kernel(
    const float* __restrict__ sampled,   // [BB][NN][4]
    const float* __restrict__ raw,       // [BB][MM][4]
    unsigned* __restrict__ rowmin,       // [BB][NN]  float bits, atomicMin
    unsigned* __restrict__ colmin)       // [BB][MM]  float bits, atomicMin
{
    __shared__ float sX[RT], sY[RT], sZ[RT], sW[RT];   // (x,y,z,|s|^2)
    __shared__ float rX[CT], rY[CT], rZ[CT], rW[CT];   // (-2x,-2y,-2z,|r|^2)
    __shared__ float cred[4][CT];

    const int b  = blockIdx.z;
    const int i0 = blockIdx.y * RT;
    const int j0 = blockIdx.x * CT;
    const int tid = threadIdx.x;
    const int tx = tid & 15, ty = tid >> 4;

    const float4* sb = (const float4*)sampled + (size_t)b * NN + i0;
    const float4* rb = (const float4*)raw     + (size_t)b * MM + j0;

    if (tid < RT) {
        float4 v = sb[tid];
        sX[tid] = v.x; sY[tid] = v.y; sZ[tid] = v.z;
        sW[tid] = fmaf(v.z, v.z, fmaf(v.y, v.y, v.x * v.x));
    } else {
        const int j = tid - RT;
        float4 v = rb[j];
        // additive mod-8 swizzle within each 8-slot group -> <=2-way banks
        const int js = (j & ~7) | ((j + (j >> 3)) & 7);
        rX[js] = -2.f * v.x; rY[js] = -2.f * v.y; rZ[js] = -2.f * v.z;
        rW[js] = fmaf(v.z, v.z, fmaf(v.y, v.y, v.x * v.x));
    }
    __syncthreads();

    float sx[8], sy[8], sz[8], sn[8];
#pragma unroll
    for (int q = 0; q < 8; ++q) {
        const int k = ty * 8 + q;                    // 4-addr broadcast, bank-distinct
        sx[q] = sX[k]; sy[q] = sY[k]; sz[q] = sZ[k]; sn[q] = sW[k];
    }
    float rx[8], ry[8], rz[8], rn[8];
#pragma unroll
    for (int r = 0; r < 8; ++r) {
        const int k = tx * 8 + ((r + tx) & 7);       // de-swizzle, <=2-way banks
        rx[r] = rX[k]; ry[r] = rY[k]; rz[r] = rZ[k]; rn[r] = rW[k];
    }
    // pin all 64 point-values in VGPRs: asm output is opaque, so the compiler
    // cannot rematerialize these from LDS inside the pair loop.
#pragma unroll
    for (int k = 0; k < 8; ++k) {
        asm volatile("" : "+v"(sx[k]), "+v"(sy[k]), "+v"(sz[k]), "+v"(sn[k]));
        asm volatile("" : "+v"(rx[k]), "+v"(ry[k]), "+v"(rz[k]), "+v"(rn[k]));
    }

    const float INF = __uint_as_float(INFBITS);
    float cmin[8] = {INF, INF, INF, INF, INF, INF, INF, INF};
    float rmin[8];

#pragma unroll
    for (int q = 0; q < 8; ++q) {
        float a[8];
#pragma unroll
        for (int r = 0; r < 8; ++r) {
            float t = sn[q] + rn[r];
            t = fmaf(sx[q], rx[r], t);
            t = fmaf(sy[q], ry[r], t);
            t = fmaf(sz[q], rz[r], t);
            a[r] = t;
            cmin[r] = fminf(cmin[r], t);
        }
        float m0 = fminf(fminf(a[0], a[1]), fminf(a[2], a[3]));
        float m1 = fminf(fminf(a[4], a[5]), fminf(a[6], a[7]));
        rmin[q] = fminf(m0, m1);
    }

    // ---- row mins: butterfly across the 16 tx lanes (in-wave) ----
#pragma unroll
    for (int m = 1; m < 16; m <<= 1) {
#pragma unroll
        for (int q = 0; q < 8; ++q)
            rmin[q] = fminf(rmin[q], __shfl_xor(rmin[q], m, 64));
    }
    if (tx == 0) {
#pragma unroll
        for (int q = 0; q < 8; ++q)
            atomicMin(&rowmin[(size_t)b * NN + i0 + ty * 8 + q],
                      __float_as_uint(fmaxf(rmin[q], 0.f)));
    }

    // ---- col mins: in-wave across ty (masks 16,32), then LDS across waves ----
#pragma unroll
    for (int m = 16; m < 64; m <<= 1) {
#pragma unroll
        for (int r = 0; r < 8; ++r)
            cmin[r] = fminf(cmin[r], __shfl_xor(cmin[r], m, 64));
    }
    const int w = tid >> 6, lane = tid & 63;
    if (lane < 16) {
#pragma unroll
        for (int r = 0; r < 8; ++r) cred[w][lane * 8 + r] = cmin[r];
    }
    __syncthreads();
    if (tid < CT) {
        float v = fminf(fminf(cred[0][tid], cred[1][tid]),
                        fminf(cred[2][tid], cred[3][tid]));
        atomicMin(&colmin[(size_t)b * MM + j0 + tid],
                  __float_as_uint(fmaxf(v, 0.f)));
    }
}

// 64 blocks: b = k>>5, slice s = k&31
__global__ __launch_bounds__(256) void reduce1_kernel(
    const unsigned* __restrict__ rowmin,
    const unsigned* __restrict__ colmin,
    float* __restrict__ part)
{
    const int k = blockIdx.x, b = k >> 5, s = k & 31;
    const int tid = threadIdx.x;
    constexpr int CS = MM / 32, RS = NN / 32;

    float sB = 0.f;
    const unsigned* cm = colmin + (size_t)b * MM + s * CS;
    for (int j = tid; j < CS; j += 256) sB += sqrtf(__uint_as_float(cm[j]));

    float sF = 0.f, mF = 0.f;
    const unsigned* rm = rowmin + (size_t)b * NN + s * RS;
    for (int i = tid; i < RS; i += 256) {
        float d = sqrtf(__uint_as_float(rm[i]));
        sF += d; mF = fmaxf(mF, d);
    }
    for (int m = 1; m < 64; m <<= 1) {
        sB += __shfl_xor(sB, m, 64);
        sF += __shfl_xor(sF, m, 64);
        mF = fmaxf(mF, __shfl_xor(mF, m, 64));
    }
    __shared__ float red[3][4];
    const int lane = tid & 63, w = tid >> 6;
    if (lane == 0) { red[0][w] = sB; red[1][w] = sF; red[2][w] = mF; }
    __syncthreads();
    if (tid == 0) {
        sB = red[0][0] + red[0][1] + red[0][2] + red[0][3];
        sF = red[1][0] + red[1][1] + red[1][2] + red[1][3];
        mF = fmaxf(fmaxf(red[2][0], red[2][1]), fmaxf(red[2][2], red[2][3]));
        part[k * 3 + 0] = sB; part[k * 3 + 1] = sF; part[k * 3 + 2] = mF;
    }
}

__global__ void reduce2_kernel(const float* __restrict__ part,
                               float* __restrict__ out)
{
    const int lane = threadIdx.x;   // 64 threads; lanes 0..31 = b0, 32..63 = b1
    float sB = part[lane * 3 + 0];
    float sF = part[lane * 3 + 1];
    float mF = part[lane * 3 + 2];
    for (int m = 1; m < 32; m <<= 1) {
        sB += __shfl_xor(sB, m, 64);
        sF += __shfl_xor(sF, m, 64);
        mF = fmaxf(mF, __shfl_xor(mF, m, 64));
    }
    float oB = __shfl_xor(sB, 32, 64);
    float oF = __shfl_xor(sF, 32, 64);
    float oM = __shfl_xor(mF, 32, 64);
    if (lane == 0) {
        float l0 = 5.f * sB / (float)MM + sF / (float)NN + mF;
        float l1 = 5.f * oB / (float)MM + oF / (float)NN + oM;
        *out = 0.5f * (l0 + l1);
    }
}

extern "C" void kernel_launch(void* const* d_in, const int* in_sizes, int n_in,
                              void* d_out, int out_size, void* d_ws, size_t ws_size,
                              hipStream_t stream) {
    const float* sampled = (const float*)d_in[0];
    const float* raw     = (const float*)d_in[1];
    unsigned* rowmin = (unsigned*)d_ws;
    unsigned* colmin = rowmin + (size_t)BB * NN;
    float*    part   = (float*)(colmin + (size_t)BB * MM);
    float*    out    = (float*)d_out;

    const int ninit = BB * NN + BB * MM;
    init_ws_kernel<<<(ninit + 255) / 256, 256, 0, stream>>>((unsigned*)d_ws, ninit);
    pair_kernel<<<dim3(MM / CT, NN / RT, BB), 256, 0, stream>>>(sampled, raw, rowmin, colmin);
    reduce1_kernel<<<64, 256, 0, stream>>>(rowmin, colmin, part);
    reduce2_kernel<<<1, 64, 0, stream>>>(part, out);
}

// Round 6
// 78.541 us; speedup vs baseline: 2.7584x; 1.2161x over previous
//
#include <hip/hip_runtime.h>
#include <math.h>

constexpr int BB = 2, NN = 4096, MM = 16384;
constexpr int RT = 128, CT = 128;        // block tile (rows=sampled, cols=raw)
constexpr unsigned INFBITS = 0x7F800000u;

__global__ __launch_bounds__(256) void init_ws_kernel(unsigned* ws, int n) {
    int i = blockIdx.x * 256 + threadIdx.x;
    if (i < n) ws[i] = INFBITS;
}

// grid (MM/CT, NN/RT, BB) = (128,32,2); block 256 = 16 tx (cols) x 16 ty (rows)
// 8x8 thread tile, float4 AoS LDS with float4-granular XOR swizzle:
//   slot(j) = (j&~7) | ((j ^ (j>>3)) & 7)
// r-reads: 2-way banks (free); s-reads: broadcast + 4 distinct groups (free).
// R4 failure was 16-way conflicts on rT (bank 4r for all tx) -> 8.26M conflict
// cycles; this swizzle removes them. ds_reads stay in-loop (compiler pipelines).
__global__ __launch_bounds__(256, 4) void pair_kernel(
    const float* __restrict__ sampled,   // [BB][NN][4]
    const float* __restrict__ raw,       // [BB][MM][4]
    unsigned* __restrict__ rowmin,       // [BB][NN]  float bits, atomicMin
    unsigned* __restrict__ colmin)       // [BB][MM]  float bits, atomicMin
{
    __shared__ float4 sT[RT];            // (x, y, z, |s|^2), swizzled slots
    __shared__ float4 rT[CT];            // (-2x, -2y, -2z, |r|^2), swizzled slots
    __shared__ float cred[4][CT];

    const int b  = blockIdx.z;
    const int i0 = blockIdx.y * RT;
    const int j0 = blockIdx.x * CT;
    const int tid = threadIdx.x;
    const int tx = tid & 15, ty = tid >> 4;

    const float4* sb = (const float4*)sampled + (size_t)b * NN + i0;
    const float4* rb = (const float4*)raw     + (size_t)b * MM + j0;

    if (tid < RT) {
        const int j = tid;
        float4 v = sb[j];
        v.w = fmaf(v.z, v.z, fmaf(v.y, v.y, v.x * v.x));
        sT[(j & ~7) | ((j ^ (j >> 3)) & 7)] = v;
    } else {
        const int j = tid - RT;
        float4 v = rb[j];
        float w = fmaf(v.z, v.z, fmaf(v.y, v.y, v.x * v.x));
        rT[(j & ~7) | ((j ^ (j >> 3)) & 7)] =
            make_float4(-2.f * v.x, -2.f * v.y, -2.f * v.z, w);
    }
    __syncthreads();

    float rx[8], ry[8], rz[8], rn[8];
#pragma unroll
    for (int r = 0; r < 8; ++r) {
        float4 v = rT[(tx * 8) | ((r ^ tx) & 7)];
        rx[r] = v.x; ry[r] = v.y; rz[r] = v.z; rn[r] = v.w;
    }

    const float INF = __uint_as_float(INFBITS);
    float cmin[8] = {INF, INF, INF, INF, INF, INF, INF, INF};
    float rmin[8];

#pragma unroll
    for (int q = 0; q < 8; ++q) {
        float4 sv = sT[(ty * 8) | ((q ^ ty) & 7)];
        float a[8];
#pragma unroll
        for (int r = 0; r < 8; ++r) {
            float t = sv.w + rn[r];
            t = fmaf(sv.x, rx[r], t);
            t = fmaf(sv.y, ry[r], t);
            t = fmaf(sv.z, rz[r], t);
            a[r] = t;
            cmin[r] = fminf(cmin[r], t);
        }
        float m0 = fminf(fminf(a[0], a[1]), fminf(a[2], a[3]));
        float m1 = fminf(fminf(a[4], a[5]), fminf(a[6], a[7]));
        rmin[q] = fminf(m0, m1);
    }

    // ---- row mins: butterfly across the 16 tx lanes (in-wave) ----
#pragma unroll
    for (int m = 1; m < 16; m <<= 1) {
#pragma unroll
        for (int q = 0; q < 8; ++q)
            rmin[q] = fminf(rmin[q], __shfl_xor(rmin[q], m, 64));
    }
    if (tx == 0) {
#pragma unroll
        for (int q = 0; q < 8; ++q)
            atomicMin(&rowmin[(size_t)b * NN + i0 + ty * 8 + q],
                      __float_as_uint(fmaxf(rmin[q], 0.f)));
    }

    // ---- col mins: in-wave across ty (masks 16,32), then LDS across waves ----
#pragma unroll
    for (int m = 16; m < 64; m <<= 1) {
#pragma unroll
        for (int r = 0; r < 8; ++r)
            cmin[r] = fminf(cmin[r], __shfl_xor(cmin[r], m, 64));
    }
    const int w = tid >> 6, lane = tid & 63;
    if (lane < 16) {
#pragma unroll
        for (int r = 0; r < 8; ++r) cred[w][lane * 8 + r] = cmin[r];
    }
    __syncthreads();
    if (tid < CT) {
        float v = fminf(fminf(cred[0][tid], cred[1][tid]),
                        fminf(cred[2][tid], cred[3][tid]));
        atomicMin(&colmin[(size_t)b * MM + j0 + tid],
                  __float_as_uint(fmaxf(v, 0.f)));
    }
}

// 64 blocks: b = k>>5, slice s = k&31
__global__ __launch_bounds__(256) void reduce1_kernel(
    const unsigned* __restrict__ rowmin,
    const unsigned* __restrict__ colmin,
    float* __restrict__ part)
{
    const int k = blockIdx.x, b = k >> 5, s = k & 31;
    const int tid = threadIdx.x;
    constexpr int CS = MM / 32, RS = NN / 32;

    float sB = 0.f;
    const unsigned* cm = colmin + (size_t)b * MM + s * CS;
    for (int j = tid; j < CS; j += 256) sB += sqrtf(__uint_as_float(cm[j]));

    float sF = 0.f, mF = 0.f;
    const unsigned* rm = rowmin + (size_t)b * NN + s * RS;
    for (int i = tid; i < RS; i += 256) {
        float d = sqrtf(__uint_as_float(rm[i]));
        sF += d; mF = fmaxf(mF, d);
    }
    for (int m = 1; m < 64; m <<= 1) {
        sB += __shfl_xor(sB, m, 64);
        sF += __shfl_xor(sF, m, 64);
        mF = fmaxf(mF, __shfl_xor(mF, m, 64));
    }
    __shared__ float red[3][4];
    const int lane = tid & 63, w = tid >> 6;
    if (lane == 0) { red[0][w] = sB; red[1][w] = sF; red[2][w] = mF; }
    __syncthreads();
    if (tid == 0) {
        sB = red[0][0] + red[0][1] + red[0][2] + red[0][3];
        sF = red[1][0] + red[1][1] + red[1][2] + red[1][3];
        mF = fmaxf(fmaxf(red[2][0], red[2][1]), fmaxf(red[2][2], red[2][3]));
        part[k * 3 + 0] = sB; part[k * 3 + 1] = sF; part[k * 3 + 2] = mF;
    }
}

__global__ void reduce2_kernel(const float* __restrict__ part,
                               float* __restrict__ out)
{
    const int lane = threadIdx.x;   // 64 threads; lanes 0..31 = b0, 32..63 = b1
    float sB = part[lane * 3 + 0];
    float sF = part[lane * 3 + 1];
    float mF = part[lane * 3 + 2];
    for (int m = 1; m < 32; m <<= 1) {
        sB += __shfl_xor(sB, m, 64);
        sF += __shfl_xor(sF, m, 64);
        mF = fmaxf(mF, __shfl_xor(mF, m, 64));
    }
    float oB = __shfl_xor(sB, 32, 64);
    float oF = __shfl_xor(sF, 32, 64);
    float oM = __shfl_xor(mF, 32, 64);
    if (lane == 0) {
        float l0 = 5.f * sB / (float)MM + sF / (float)NN + mF;
        float l1 = 5.f * oB / (float)MM + oF / (float)NN + oM;
        *out = 0.5f * (l0 + l1);
    }
}

extern "C" void kernel_launch(void* const* d_in, const int* in_sizes, int n_in,
                              void* d_out, int out_size, void* d_ws, size_t ws_size,
                              hipStream_t stream) {
    const float* sampled = (const float*)d_in[0];
    const float* raw     = (const float*)d_in[1];
    unsigned* rowmin = (unsigned*)d_ws;
    unsigned* colmin = rowmin + (size_t)BB * NN;
    float*    part   = (float*)(colmin + (size_t)BB * MM);
    float*    out    = (float*)d_out;

    const int ninit = BB * NN + BB * MM;
    init_ws_kernel<<<(ninit + 255) / 256, 256, 0, stream>>>((unsigned*)d_ws, ninit);
    pair_kernel<<<dim3(MM / CT, NN / RT, BB), 256, 0, stream>>>(sampled, raw, rowmin, colmin);
    reduce1_kernel<<<64, 256, 0, stream>>>(rowmin, colmin, part);
    reduce2_kernel<<<1, 64, 0, stream>>>(part, out);
}